// Round 1
// baseline (389.040 us; speedup 1.0000x reference)
//
#include <hip/hip_runtime.h>

// MSDeformAttn fp32 baseline.
// Fixed problem geometry (matches reference setup_inputs()):
#define NB 2
#define NQ 10000
#define DM 256
#define NHEADS 8
#define NLEV 4
#define NPTS 4
#define DHEAD 32
#define LEN_IN 5440   // 64*64 + 32*32 + 16*16 + 8*8

// -------- generic row-block GEMM: Y[r,:256] = X[r,:256] @ W[256,256] + b --------
// 8 rows per block, 256 threads (one output column per thread).
__global__ __launch_bounds__(256) void rowgemm256(const float* __restrict__ X,
                                                  const float* __restrict__ W,
                                                  const float* __restrict__ b,
                                                  float* __restrict__ Y) {
    __shared__ float xs[8][DM];
    const int t = threadIdx.x;
    const long r0 = (long)blockIdx.x * 8;
    #pragma unroll
    for (int i = 0; i < 8; ++i) xs[i][t] = X[(r0 + i) * DM + t];
    __syncthreads();
    float acc[8];
    #pragma unroll
    for (int i = 0; i < 8; ++i) acc[i] = 0.f;
    #pragma unroll 4
    for (int k = 0; k < DM; ++k) {
        const float w = W[k * DM + t];
        #pragma unroll
        for (int i = 0; i < 8; ++i) acc[i] = fmaf(xs[i][k], w, acc[i]);
    }
    const float bb = b[t];
    #pragma unroll
    for (int i = 0; i < 8; ++i) Y[(r0 + i) * DM + t] = acc[i] + bb;
}

// -------- fused: off/attn projection + softmax + deformable sampling --------
// One block handles QPB=8 queries. 256 threads.
__device__ __forceinline__ float samplev(const float* __restrict__ vbase,
                                         int st, int H, int W,
                                         int xi, int yi, int c) {
    const bool valid = (xi >= 0) & (xi < W) & (yi >= 0) & (yi < H);
    const int xc = min(max(xi, 0), W - 1);
    const int yc = min(max(yi, 0), H - 1);
    const float v = vbase[(size_t)(st + yc * W + xc) * DM + c];
    return valid ? v : 0.0f;
}

__global__ __launch_bounds__(256) void fused_sample(const float* __restrict__ query,
                                                    const float* __restrict__ refp,
                                                    const float* __restrict__ W_off,
                                                    const float* __restrict__ b_off,
                                                    const float* __restrict__ W_attn,
                                                    const float* __restrict__ b_attn,
                                                    const float* __restrict__ value,
                                                    float* __restrict__ out_pre) {
    constexpr int QPB = 8;
    __shared__ float qs[QPB][DM];
    __shared__ float offs[QPB][DM];
    __shared__ float attns[QPB][NHEADS * NLEV * NPTS]; // [8][128]
    __shared__ float refs[QPB][NLEV][2];

    const int t = threadIdx.x;
    const int blk = blockIdx.x;                 // 0..2499
    const int n = blk / (NQ / QPB);
    const int q0 = (blk % (NQ / QPB)) * QPB;

    const float* qbase = query + ((size_t)n * NQ + q0) * DM;
    #pragma unroll
    for (int i = 0; i < QPB; ++i) qs[i][t] = qbase[(size_t)i * DM + t];
    if (t < QPB * NLEV * 2) {
        const int i = t / (NLEV * 2);
        const int rem = t % (NLEV * 2);
        refs[i][rem / 2][rem % 2] =
            refp[(((size_t)n * NQ + q0 + i) * NLEV) * 2 + rem];
    }
    __syncthreads();

    // ---- offset projection: each thread computes column t for 8 queries ----
    {
        float acc[QPB];
        #pragma unroll
        for (int i = 0; i < QPB; ++i) acc[i] = 0.f;
        #pragma unroll 4
        for (int k = 0; k < DM; ++k) {
            const float w = W_off[k * DM + t];
            #pragma unroll
            for (int i = 0; i < QPB; ++i) acc[i] = fmaf(qs[i][k], w, acc[i]);
        }
        const float bb = b_off[t];
        #pragma unroll
        for (int i = 0; i < QPB; ++i) offs[i][t] = acc[i] + bb;
    }
    // ---- attn projection: 128 cols; low half threads -> queries 0..3, high -> 4..7 ----
    {
        float acc[QPB / 2];
        #pragma unroll
        for (int j = 0; j < QPB / 2; ++j) acc[j] = 0.f;
        const int c = t & 127;
        const int ibase = (t >> 7) * (QPB / 2);
        #pragma unroll 4
        for (int k = 0; k < DM; ++k) {
            const float w = W_attn[k * 128 + c];
            #pragma unroll
            for (int j = 0; j < QPB / 2; ++j) acc[j] = fmaf(qs[ibase + j][k], w, acc[j]);
        }
        const float bb = b_attn[c];
        #pragma unroll
        for (int j = 0; j < QPB / 2; ++j) attns[ibase + j][c] = acc[j] + bb;
    }
    __syncthreads();

    // ---- softmax over 16 (level,point) entries per (query, head) ----
    if (t < QPB * NHEADS) {
        const int i = t >> 3, h = t & 7;
        float* a = &attns[i][h * 16];
        float m = a[0];
        #pragma unroll
        for (int j = 1; j < 16; ++j) m = fmaxf(m, a[j]);
        float s = 0.f;
        #pragma unroll
        for (int j = 0; j < 16; ++j) { const float e = __expf(a[j] - m); a[j] = e; s += e; }
        const float inv = 1.0f / s;
        #pragma unroll
        for (int j = 0; j < 16; ++j) a[j] *= inv;
    }
    __syncthreads();

    // ---- deformable sampling: thread t -> (head h, channel d) ----
    const int h = t >> 5;   // 0..7
    const int d = t & 31;   // 0..31
    const int c = h * DHEAD + d;  // == t
    const float* vbase = value + (size_t)n * LEN_IN * DM;

    float acc[QPB];
    #pragma unroll
    for (int i = 0; i < QPB; ++i) acc[i] = 0.f;

    for (int i = 0; i < QPB; ++i) {
        #pragma unroll
        for (int lvl = 0; lvl < NLEV; ++lvl) {
            constexpr int HS[4] = {64, 32, 16, 8};
            constexpr int WS[4] = {64, 32, 16, 8};
            constexpr int ST[4] = {0, 4096, 5120, 5376};
            const int H_ = HS[lvl], W_ = WS[lvl], st = ST[lvl];
            const float rx = refs[i][lvl][0];
            const float ry = refs[i][lvl][1];
            const float invW = 1.0f / (float)W_;
            const float invH = 1.0f / (float)H_;
            #pragma unroll
            for (int pt = 0; pt < NPTS; ++pt) {
                const int oidx = ((h * NLEV + lvl) * NPTS + pt) * 2;
                const float lx = rx + offs[i][oidx]     * invW;
                const float ly = ry + offs[i][oidx + 1] * invH;
                const float aw = attns[i][h * 16 + lvl * 4 + pt];
                const float x = lx * (float)W_ - 0.5f;
                const float y = ly * (float)H_ - 0.5f;
                const float x0f = floorf(x);
                const float y0f = floorf(y);
                const float wx = x - x0f;
                const float wy = y - y0f;
                const int x0 = (int)x0f;
                const int y0 = (int)y0f;
                const float v00 = samplev(vbase, st, H_, W_, x0,     y0,     c);
                const float v01 = samplev(vbase, st, H_, W_, x0 + 1, y0,     c);
                const float v10 = samplev(vbase, st, H_, W_, x0,     y0 + 1, c);
                const float v11 = samplev(vbase, st, H_, W_, x0 + 1, y0 + 1, c);
                const float bil = v00 * (1.f - wx) * (1.f - wy)
                                + v01 * wx         * (1.f - wy)
                                + v10 * (1.f - wx) * wy
                                + v11 * wx         * wy;
                acc[i] = fmaf(aw, bil, acc[i]);
            }
        }
    }
    #pragma unroll
    for (int i = 0; i < QPB; ++i)
        out_pre[((size_t)n * NQ + q0 + i) * DM + t] = acc[i];
}

extern "C" void kernel_launch(void* const* d_in, const int* in_sizes, int n_in,
                              void* d_out, int out_size, void* d_ws, size_t ws_size,
                              hipStream_t stream) {
    const float* query  = (const float*)d_in[0];
    const float* refp   = (const float*)d_in[1];
    const float* inflat = (const float*)d_in[2];
    // d_in[3] spatial shapes, d_in[4] level start: geometry is hardcoded.
    const float* W_value = (const float*)d_in[5];
    const float* b_value = (const float*)d_in[6];
    const float* W_off   = (const float*)d_in[7];
    const float* b_off   = (const float*)d_in[8];
    const float* W_attn  = (const float*)d_in[9];
    const float* b_attn  = (const float*)d_in[10];
    const float* W_out   = (const float*)d_in[11];
    const float* b_out   = (const float*)d_in[12];
    float* out = (float*)d_out;

    // workspace: value (2*5440*256 f32 = 11,141,120 B), then out_pre (20,480,000 B)
    float* value   = (float*)d_ws;
    float* out_pre = (float*)((char*)d_ws + 11141120);

    // 1) value projection: 10880 rows / 8 = 1360 blocks
    rowgemm256<<<1360, 256, 0, stream>>>(inflat, W_value, b_value, value);
    // 2) fused off/attn proj + softmax + sampling: 20000 queries / 8 = 2500 blocks
    fused_sample<<<2500, 256, 0, stream>>>(query, refp, W_off, b_off,
                                           W_attn, b_attn, value, out_pre);
    // 3) output projection: 20000 rows / 8 = 2500 blocks
    rowgemm256<<<2500, 256, 0, stream>>>(out_pre, W_out, b_out, out);
}

// Round 2
// 224.286 us; speedup vs baseline: 1.7346x; 1.7346x over previous
//
#include <hip/hip_runtime.h>

// MSDeformAttn fp32 — round 1: float4-vectorized sampling stage.
#define NB 2
#define NQ 10000
#define DM 256
#define NHEADS 8
#define NLEV 4
#define NPTS 4
#define DHEAD 32
#define LEN_IN 5440   // 64*64 + 32*32 + 16*16 + 8*8

// -------- generic row-block GEMM: Y[r,:256] = X[r,:256] @ W[256,256] + b --------
__global__ __launch_bounds__(256) void rowgemm256(const float* __restrict__ X,
                                                  const float* __restrict__ W,
                                                  const float* __restrict__ b,
                                                  float* __restrict__ Y) {
    __shared__ float xs[8][DM];
    const int t = threadIdx.x;
    const long r0 = (long)blockIdx.x * 8;
    #pragma unroll
    for (int i = 0; i < 8; ++i) xs[i][t] = X[(r0 + i) * DM + t];
    __syncthreads();
    float acc[8];
    #pragma unroll
    for (int i = 0; i < 8; ++i) acc[i] = 0.f;
    #pragma unroll 4
    for (int k = 0; k < DM; ++k) {
        const float w = W[k * DM + t];
        #pragma unroll
        for (int i = 0; i < 8; ++i) acc[i] = fmaf(xs[i][k], w, acc[i]);
    }
    const float bb = b[t];
    #pragma unroll
    for (int i = 0; i < 8; ++i) Y[(r0 + i) * DM + t] = acc[i] + bb;
}

// -------- fused: off/attn projection + softmax + float4 deformable sampling ----
__global__ __launch_bounds__(256) void fused_sample(const float* __restrict__ query,
                                                    const float* __restrict__ refp,
                                                    const float* __restrict__ W_off,
                                                    const float* __restrict__ b_off,
                                                    const float* __restrict__ W_attn,
                                                    const float* __restrict__ b_attn,
                                                    const float* __restrict__ value,
                                                    float* __restrict__ out_pre) {
    constexpr int QPB = 8;
    __shared__ float qs[QPB][DM];
    __shared__ float offs[QPB][DM];
    __shared__ float attns[QPB][NHEADS * NLEV * NPTS]; // [8][128]
    __shared__ float refs[QPB][NLEV][2];

    const int t = threadIdx.x;
    const int blk = blockIdx.x;                 // 0..2499
    const int n = blk / (NQ / QPB);
    const int q0 = (blk % (NQ / QPB)) * QPB;

    const float* qbase = query + ((size_t)n * NQ + q0) * DM;
    #pragma unroll
    for (int i = 0; i < QPB; ++i) qs[i][t] = qbase[(size_t)i * DM + t];
    if (t < QPB * NLEV * 2) {
        const int i = t / (NLEV * 2);
        const int rem = t % (NLEV * 2);
        refs[i][rem / 2][rem % 2] =
            refp[(((size_t)n * NQ + q0 + i) * NLEV) * 2 + rem];
    }
    __syncthreads();

    // ---- offset projection: thread t = output column ----
    {
        float acc[QPB];
        #pragma unroll
        for (int i = 0; i < QPB; ++i) acc[i] = 0.f;
        #pragma unroll 4
        for (int k = 0; k < DM; ++k) {
            const float w = W_off[k * DM + t];
            #pragma unroll
            for (int i = 0; i < QPB; ++i) acc[i] = fmaf(qs[i][k], w, acc[i]);
        }
        const float bb = b_off[t];
        #pragma unroll
        for (int i = 0; i < QPB; ++i) offs[i][t] = acc[i] + bb;
    }
    // ---- attn projection: 128 cols; low/high half of threads split queries ----
    {
        float acc[QPB / 2];
        #pragma unroll
        for (int j = 0; j < QPB / 2; ++j) acc[j] = 0.f;
        const int c = t & 127;
        const int ibase = (t >> 7) * (QPB / 2);
        #pragma unroll 4
        for (int k = 0; k < DM; ++k) {
            const float w = W_attn[k * 128 + c];
            #pragma unroll
            for (int j = 0; j < QPB / 2; ++j) acc[j] = fmaf(qs[ibase + j][k], w, acc[j]);
        }
        const float bb = b_attn[c];
        #pragma unroll
        for (int j = 0; j < QPB / 2; ++j) attns[ibase + j][c] = acc[j] + bb;
    }
    __syncthreads();

    // ---- softmax over 16 (level,point) entries per (query, head) ----
    if (t < QPB * NHEADS) {
        const int i = t >> 3, h = t & 7;
        float* a = &attns[i][h * 16];
        float m = a[0];
        #pragma unroll
        for (int j = 1; j < 16; ++j) m = fmaxf(m, a[j]);
        float s = 0.f;
        #pragma unroll
        for (int j = 0; j < 16; ++j) { const float e = __expf(a[j] - m); a[j] = e; s += e; }
        const float inv = 1.0f / s;
        #pragma unroll
        for (int j = 0; j < 16; ++j) a[j] *= inv;
    }
    __syncthreads();

    // ---- sampling: thread -> (query-slot, head, float4 channel group) ----
    // t = qpar*64 + h*8 + g ; qpar in 0..3, serial queries i = qpar, qpar+4.
    const int qpar = t >> 6;
    const int lane = t & 63;
    const int h = lane >> 3;       // 0..7
    const int g = lane & 7;        // 0..7  -> channels h*32 + g*4 .. +3
    const float4* __restrict__ vbase4 =
        (const float4*)(value + (size_t)n * LEN_IN * DM) + (h * 8 + g);
    float4* __restrict__ out4 =
        (float4*)(out_pre + ((size_t)n * NQ + q0) * DM) + (h * 8 + g);

    constexpr int HS[4] = {64, 32, 16, 8};
    constexpr int ST[4] = {0, 4096, 5120, 5376};

    #pragma unroll
    for (int ii = 0; ii < 2; ++ii) {
        const int i = qpar + ii * 4;
        float4 acc = make_float4(0.f, 0.f, 0.f, 0.f);
        #pragma unroll
        for (int lvl = 0; lvl < NLEV; ++lvl) {
            const int H_ = HS[lvl], W_ = HS[lvl], st = ST[lvl];
            const float fW = (float)W_, fH = (float)H_;
            const float invW = 1.0f / fW, invH = 1.0f / fH;
            const float rx = refs[i][lvl][0];
            const float ry = refs[i][lvl][1];
            #pragma unroll
            for (int pt = 0; pt < NPTS; ++pt) {
                const int oidx = ((h * NLEV + lvl) * NPTS + pt) * 2;
                const float lx = rx + offs[i][oidx]     * invW;
                const float ly = ry + offs[i][oidx + 1] * invH;
                const float aw = attns[i][h * 16 + lvl * 4 + pt];
                const float x = lx * fW - 0.5f;
                const float y = ly * fH - 0.5f;
                const float x0f = floorf(x);
                const float y0f = floorf(y);
                const float wx = x - x0f;
                const float wy = y - y0f;
                const int x0 = (int)x0f;
                const int y0 = (int)y0f;
                const int x1 = x0 + 1, y1 = y0 + 1;
                const int xc0 = min(max(x0, 0), W_ - 1);
                const int xc1 = min(max(x1, 0), W_ - 1);
                const int yc0 = min(max(y0, 0), H_ - 1);
                const int yc1 = min(max(y1, 0), H_ - 1);
                const bool vx0 = (x0 >= 0) & (x0 < W_);
                const bool vx1 = (x1 >= 0) & (x1 < W_);
                const bool vy0 = (y0 >= 0) & (y0 < H_);
                const bool vy1 = (y1 >= 0) & (y1 < H_);
                // per-corner weights (attn folded in); zero out invalid corners
                const float w00 = (vx0 & vy0) ? aw * (1.f - wx) * (1.f - wy) : 0.f;
                const float w01 = (vx1 & vy0) ? aw * wx         * (1.f - wy) : 0.f;
                const float w10 = (vx0 & vy1) ? aw * (1.f - wx) * wy         : 0.f;
                const float w11 = (vx1 & vy1) ? aw * wx         * wy         : 0.f;
                const int r0i = st + yc0 * W_;
                const int r1i = st + yc1 * W_;
                const float4 v00 = vbase4[(size_t)(r0i + xc0) * 64];
                const float4 v01 = vbase4[(size_t)(r0i + xc1) * 64];
                const float4 v10 = vbase4[(size_t)(r1i + xc0) * 64];
                const float4 v11 = vbase4[(size_t)(r1i + xc1) * 64];
                acc.x = fmaf(w00, v00.x, fmaf(w01, v01.x, fmaf(w10, v10.x, fmaf(w11, v11.x, acc.x))));
                acc.y = fmaf(w00, v00.y, fmaf(w01, v01.y, fmaf(w10, v10.y, fmaf(w11, v11.y, acc.y))));
                acc.z = fmaf(w00, v00.z, fmaf(w01, v01.z, fmaf(w10, v10.z, fmaf(w11, v11.z, acc.z))));
                acc.w = fmaf(w00, v00.w, fmaf(w01, v01.w, fmaf(w10, v10.w, fmaf(w11, v11.w, acc.w))));
            }
        }
        out4[(size_t)i * 64] = acc;
    }
}

extern "C" void kernel_launch(void* const* d_in, const int* in_sizes, int n_in,
                              void* d_out, int out_size, void* d_ws, size_t ws_size,
                              hipStream_t stream) {
    const float* query  = (const float*)d_in[0];
    const float* refp   = (const float*)d_in[1];
    const float* inflat = (const float*)d_in[2];
    const float* W_value = (const float*)d_in[5];
    const float* b_value = (const float*)d_in[6];
    const float* W_off   = (const float*)d_in[7];
    const float* b_off   = (const float*)d_in[8];
    const float* W_attn  = (const float*)d_in[9];
    const float* b_attn  = (const float*)d_in[10];
    const float* W_out   = (const float*)d_in[11];
    const float* b_out   = (const float*)d_in[12];
    float* out = (float*)d_out;

    float* value   = (float*)d_ws;                          // 11,141,120 B
    float* out_pre = (float*)((char*)d_ws + 11141120);      // 20,480,000 B

    rowgemm256<<<1360, 256, 0, stream>>>(inflat, W_value, b_value, value);
    fused_sample<<<2500, 256, 0, stream>>>(query, refp, W_off, b_off,
                                           W_attn, b_attn, value, out_pre);
    rowgemm256<<<2500, 256, 0, stream>>>(out_pre, W_out, b_out, out);
}

// Round 3
// 132.859 us; speedup vs baseline: 2.9282x; 1.6881x over previous
//
#include <hip/hip_runtime.h>

// MSDeformAttn — round 2: fp16-MFMA projections + slim fp16 sampling kernel.
#define NB 2
#define NQ 10000
#define DM 256
#define NHEADS 8
#define NLEV 4
#define NPTS 4
#define DHEAD 32
#define LEN_IN 5440   // 64*64 + 32*32 + 16*16 + 8*8

typedef _Float16 f16x8 __attribute__((ext_vector_type(8)));
typedef _Float16 f16x4 __attribute__((ext_vector_type(4)));
typedef float    f32x4 __attribute__((ext_vector_type(4)));

// ---------------- weight pre-swizzle: fp32 W[K][Nw] -> fp16 MFMA B-fragment order ----
// dst layout: tile (nt,kt) at ((nt*8 + kt)*64 + lane)*8 halves;
// lane l holds W[kt*32 + (l>>4)*8 + j][nt*16 + (l&15)], j=0..7.
__device__ __forceinline__ void swz_one(const float* __restrict__ W, int Nw,
                                        int srcCol, int kbase,
                                        _Float16* __restrict__ dst) {
    f16x8 v;
    #pragma unroll
    for (int j = 0; j < 8; ++j) v[j] = (_Float16)W[(size_t)(kbase + j) * Nw + srcCol];
    *(f16x8*)dst = v;
}

__global__ __launch_bounds__(256) void preconvert(const float* __restrict__ Wv,
                                                  const float* __restrict__ Wo,
                                                  const float* __restrict__ Wa,
                                                  const float* __restrict__ Wout,
                                                  _Float16* __restrict__ Wv_swz,
                                                  _Float16* __restrict__ Wofa_swz,
                                                  _Float16* __restrict__ Wout_swz) {
    const int tid = blockIdx.x * 256 + threadIdx.x;
    int local, base;
    // W_value: 16 ntiles * 8 kt * 64 lanes = 8192 threads
    if (tid < 8192) {
        local = tid;
        const int lane = local & 63, t = local >> 6, kt = t & 7, nt = t >> 3;
        const int kbase = kt * 32 + (lane >> 4) * 8;
        swz_one(Wv, 256, nt * 16 + (lane & 15), kbase,
                Wv_swz + ((size_t)(nt * 8 + kt) * 64 + lane) * 8);
    } else if (tid < 16384) {            // W_off -> ofa ntiles 0..15
        local = tid - 8192;
        const int lane = local & 63, t = local >> 6, kt = t & 7, nt = t >> 3;
        const int kbase = kt * 32 + (lane >> 4) * 8;
        swz_one(Wo, 256, nt * 16 + (lane & 15), kbase,
                Wofa_swz + ((size_t)(nt * 8 + kt) * 64 + lane) * 8);
    } else if (tid < 20480) {            // W_attn -> ofa ntiles 16..23
        local = tid - 16384;
        const int lane = local & 63, t = local >> 6, kt = t & 7, nt = t >> 3;
        const int kbase = kt * 32 + (lane >> 4) * 8;
        swz_one(Wa, 128, nt * 16 + (lane & 15), kbase,
                Wofa_swz + ((size_t)((16 + nt) * 8 + kt) * 64 + lane) * 8);
    } else if (tid < 28672) {            // W_out
        local = tid - 20480;
        const int lane = local & 63, t = local >> 6, kt = t & 7, nt = t >> 3;
        const int kbase = kt * 32 + (lane >> 4) * 8;
        swz_one(Wout, 256, nt * 16 + (lane & 15), kbase,
                Wout_swz + ((size_t)(nt * 8 + kt) * 64 + lane) * 8);
    }
    (void)base;
}

// ---------------- MFMA GEMM: C[M][N] = A[M][256] @ W + bias ----------------
// 64x64 block tile, 4 waves (2x2), each wave 32x32 (2x2 fragments of 16x16).
// No LDS: A fragments loaded straight from global; B from pre-swizzled fp16.
template<bool A_F32, bool OUT_F16>
__global__ __launch_bounds__(256) void gemm_mfma(const void* __restrict__ A_,
                                                 const _Float16* __restrict__ Wswz,
                                                 const float* __restrict__ bias0,
                                                 const float* __restrict__ bias1,
                                                 int bsplit,
                                                 void* __restrict__ C_,
                                                 int M, int N) {
    const int lane = threadIdx.x & 63;
    const int w = threadIdx.x >> 6;
    const int wm = w & 1, wn = w >> 1;
    const int m0 = blockIdx.x * 64 + wm * 32;
    const int n0 = blockIdx.y * 64 + wn * 32;
    const int r = lane & 15;
    const int klane = (lane >> 4) * 8;

    const int rc0 = min(m0 + r, M - 1);
    const int rc1 = min(m0 + 16 + r, M - 1);
    const int ntile0 = n0 >> 4;

    f32x4 acc[2][2] = {};

    #pragma unroll
    for (int kt = 0; kt < 8; ++kt) {
        f16x8 a0, a1;
        if constexpr (A_F32) {
            const float* A = (const float*)A_;
            const float4* p0 = (const float4*)(A + (size_t)rc0 * 256 + kt * 32 + klane);
            const float4* p1 = (const float4*)(A + (size_t)rc1 * 256 + kt * 32 + klane);
            const float4 l0 = p0[0], h0 = p0[1];
            const float4 l1 = p1[0], h1 = p1[1];
            a0[0] = (_Float16)l0.x; a0[1] = (_Float16)l0.y; a0[2] = (_Float16)l0.z; a0[3] = (_Float16)l0.w;
            a0[4] = (_Float16)h0.x; a0[5] = (_Float16)h0.y; a0[6] = (_Float16)h0.z; a0[7] = (_Float16)h0.w;
            a1[0] = (_Float16)l1.x; a1[1] = (_Float16)l1.y; a1[2] = (_Float16)l1.z; a1[3] = (_Float16)l1.w;
            a1[4] = (_Float16)h1.x; a1[5] = (_Float16)h1.y; a1[6] = (_Float16)h1.z; a1[7] = (_Float16)h1.w;
        } else {
            const _Float16* A = (const _Float16*)A_;
            a0 = *(const f16x8*)(A + (size_t)rc0 * 256 + kt * 32 + klane);
            a1 = *(const f16x8*)(A + (size_t)rc1 * 256 + kt * 32 + klane);
        }
        const f16x8 b0 = *(const f16x8*)(Wswz + ((size_t)((ntile0 + 0) * 8 + kt) * 64 + lane) * 8);
        const f16x8 b1 = *(const f16x8*)(Wswz + ((size_t)((ntile0 + 1) * 8 + kt) * 64 + lane) * 8);
        acc[0][0] = __builtin_amdgcn_mfma_f32_16x16x32_f16(a0, b0, acc[0][0], 0, 0, 0);
        acc[0][1] = __builtin_amdgcn_mfma_f32_16x16x32_f16(a0, b1, acc[0][1], 0, 0, 0);
        acc[1][0] = __builtin_amdgcn_mfma_f32_16x16x32_f16(a1, b0, acc[1][0], 0, 0, 0);
        acc[1][1] = __builtin_amdgcn_mfma_f32_16x16x32_f16(a1, b1, acc[1][1], 0, 0, 0);
    }

    #pragma unroll
    for (int j = 0; j < 2; ++j) {
        const int col = n0 + j * 16 + r;
        const float bb = (col < bsplit) ? bias0[col] : bias1[col - bsplit];
        #pragma unroll
        for (int i = 0; i < 2; ++i) {
            #pragma unroll
            for (int rr = 0; rr < 4; ++rr) {
                const int row = m0 + i * 16 + (lane >> 4) * 4 + rr;
                if (row < M) {
                    const float v = acc[i][j][rr] + bb;
                    if constexpr (OUT_F16)
                        ((_Float16*)C_)[(size_t)row * N + col] = (_Float16)v;
                    else
                        ((float*)C_)[(size_t)row * N + col] = v;
                }
            }
        }
    }
}

// ---------------- sampling: softmax + bilinear gather (fp16 value/ofa) ------
__global__ __launch_bounds__(256) void sample_kernel(const float* __restrict__ refp,
                                                     const _Float16* __restrict__ ofa,
                                                     const _Float16* __restrict__ value,
                                                     _Float16* __restrict__ out_pre) {
    constexpr int QPB = 8;
    __shared__ float offs[QPB][DM];
    __shared__ float attns[QPB][NHEADS * NLEV * NPTS]; // [8][128]
    __shared__ float refs[QPB][NLEV][2];

    const int t = threadIdx.x;
    const int blk = blockIdx.x;
    const int n = blk / (NQ / QPB);
    const int q0 = (blk % (NQ / QPB)) * QPB;
    const size_t qb = (size_t)n * NQ + q0;

    #pragma unroll
    for (int i = 0; i < QPB; ++i)
        offs[i][t] = (float)ofa[(qb + i) * 384 + t];
    if (t < 128) {
        #pragma unroll
        for (int i = 0; i < QPB; ++i)
            attns[i][t] = (float)ofa[(qb + i) * 384 + 256 + t];
    }
    if (t < QPB * NLEV * 2) {
        const int i = t / (NLEV * 2);
        const int rem = t % (NLEV * 2);
        refs[i][rem / 2][rem % 2] = refp[(qb + i) * NLEV * 2 + rem];
    }
    __syncthreads();

    if (t < QPB * NHEADS) {
        const int i = t >> 3, h = t & 7;
        float* a = &attns[i][h * 16];
        float m = a[0];
        #pragma unroll
        for (int j = 1; j < 16; ++j) m = fmaxf(m, a[j]);
        float s = 0.f;
        #pragma unroll
        for (int j = 0; j < 16; ++j) { const float e = __expf(a[j] - m); a[j] = e; s += e; }
        const float inv = 1.0f / s;
        #pragma unroll
        for (int j = 0; j < 16; ++j) a[j] *= inv;
    }
    __syncthreads();

    // thread -> (query-slot qpar, head h, half4 channel group g)
    const int qpar = t >> 6;
    const int lane = t & 63;
    const int h = lane >> 3;
    const int g = lane & 7;
    const f16x4* __restrict__ vbase4 =
        (const f16x4*)(value + (size_t)n * LEN_IN * DM) + (h * 8 + g);

    constexpr int HS[4] = {64, 32, 16, 8};
    constexpr int ST[4] = {0, 4096, 5120, 5376};

    #pragma unroll
    for (int ii = 0; ii < 2; ++ii) {
        const int i = qpar + ii * 4;
        float4 acc = make_float4(0.f, 0.f, 0.f, 0.f);
        #pragma unroll
        for (int lvl = 0; lvl < NLEV; ++lvl) {
            const int H_ = HS[lvl], W_ = HS[lvl], st = ST[lvl];
            const float fW = (float)W_, fH = (float)H_;
            const float invW = 1.0f / fW, invH = 1.0f / fH;
            const float rx = refs[i][lvl][0];
            const float ry = refs[i][lvl][1];
            #pragma unroll
            for (int pt = 0; pt < NPTS; ++pt) {
                const int oidx = ((h * NLEV + lvl) * NPTS + pt) * 2;
                const float lx = rx + offs[i][oidx]     * invW;
                const float ly = ry + offs[i][oidx + 1] * invH;
                const float aw = attns[i][h * 16 + lvl * 4 + pt];
                const float x = lx * fW - 0.5f;
                const float y = ly * fH - 0.5f;
                const float x0f = floorf(x);
                const float y0f = floorf(y);
                const float wx = x - x0f;
                const float wy = y - y0f;
                const int x0 = (int)x0f;
                const int y0 = (int)y0f;
                const int x1 = x0 + 1, y1 = y0 + 1;
                const int xc0 = min(max(x0, 0), W_ - 1);
                const int xc1 = min(max(x1, 0), W_ - 1);
                const int yc0 = min(max(y0, 0), H_ - 1);
                const int yc1 = min(max(y1, 0), H_ - 1);
                const bool vx0 = (x0 >= 0) & (x0 < W_);
                const bool vx1 = (x1 >= 0) & (x1 < W_);
                const bool vy0 = (y0 >= 0) & (y0 < H_);
                const bool vy1 = (y1 >= 0) & (y1 < H_);
                const float w00 = (vx0 & vy0) ? aw * (1.f - wx) * (1.f - wy) : 0.f;
                const float w01 = (vx1 & vy0) ? aw * wx         * (1.f - wy) : 0.f;
                const float w10 = (vx0 & vy1) ? aw * (1.f - wx) * wy         : 0.f;
                const float w11 = (vx1 & vy1) ? aw * wx         * wy         : 0.f;
                const int r0i = st + yc0 * W_;
                const int r1i = st + yc1 * W_;
                const f16x4 v00 = vbase4[(size_t)(r0i + xc0) * 64];
                const f16x4 v01 = vbase4[(size_t)(r0i + xc1) * 64];
                const f16x4 v10 = vbase4[(size_t)(r1i + xc0) * 64];
                const f16x4 v11 = vbase4[(size_t)(r1i + xc1) * 64];
                acc.x = fmaf(w00, (float)v00[0], fmaf(w01, (float)v01[0], fmaf(w10, (float)v10[0], fmaf(w11, (float)v11[0], acc.x))));
                acc.y = fmaf(w00, (float)v00[1], fmaf(w01, (float)v01[1], fmaf(w10, (float)v10[1], fmaf(w11, (float)v11[1], acc.y))));
                acc.z = fmaf(w00, (float)v00[2], fmaf(w01, (float)v01[2], fmaf(w10, (float)v10[2], fmaf(w11, (float)v11[2], acc.z))));
                acc.w = fmaf(w00, (float)v00[3], fmaf(w01, (float)v01[3], fmaf(w10, (float)v10[3], fmaf(w11, (float)v11[3], acc.w))));
            }
        }
        f16x4 o;
        o[0] = (_Float16)acc.x; o[1] = (_Float16)acc.y;
        o[2] = (_Float16)acc.z; o[3] = (_Float16)acc.w;
        ((f16x4*)(out_pre + (qb + i) * DM))[h * 8 + g] = o;
    }
}

extern "C" void kernel_launch(void* const* d_in, const int* in_sizes, int n_in,
                              void* d_out, int out_size, void* d_ws, size_t ws_size,
                              hipStream_t stream) {
    const float* query  = (const float*)d_in[0];
    const float* refp   = (const float*)d_in[1];
    const float* inflat = (const float*)d_in[2];
    const float* W_value = (const float*)d_in[5];
    const float* b_value = (const float*)d_in[6];
    const float* W_off   = (const float*)d_in[7];
    const float* b_off   = (const float*)d_in[8];
    const float* W_attn  = (const float*)d_in[9];
    const float* b_attn  = (const float*)d_in[10];
    const float* W_out   = (const float*)d_in[11];
    const float* b_out   = (const float*)d_in[12];
    float* out = (float*)d_out;

    // ws layout (bytes):
    //   value_h   @ 0          : 2*5440*256*2  = 5,570,560
    //   ofa_h     @ 5,570,560  : 2*10000*384*2 = 15,360,000   (ends 20,930,560)
    //   out_pre_h @ 20,930,560 : 2*10000*256*2 = 10,240,000   (ends 31,170,560)
    //   Wv_swz    @ 20,930,560 : 131,072   (aliases out_pre — dead before sampling)
    //   Wofa_swz  @ 21,061,632 : 196,608   (aliases out_pre — dead before sampling)
    //   Wout_swz  @ 31,170,560 : 131,072   (ends 31,301,632)
    char* ws = (char*)d_ws;
    _Float16* value_h   = (_Float16*)(ws);
    _Float16* ofa_h     = (_Float16*)(ws + 5570560);
    _Float16* out_pre_h = (_Float16*)(ws + 20930560);
    _Float16* Wv_swz    = (_Float16*)(ws + 20930560);
    _Float16* Wofa_swz  = (_Float16*)(ws + 21061632);
    _Float16* Wout_swz  = (_Float16*)(ws + 31170560);

    preconvert<<<112, 256, 0, stream>>>(W_value, W_off, W_attn, W_out,
                                        Wv_swz, Wofa_swz, Wout_swz);
    // value projection: [10880 x 256] = inflat @ W_value
    gemm_mfma<true, true><<<dim3(170, 4), 256, 0, stream>>>(
        inflat, Wv_swz, b_value, b_value, 256, value_h, 10880, 256);
    // off+attn projection: [20000 x 384] = query @ [W_off | W_attn]
    gemm_mfma<true, true><<<dim3(313, 6), 256, 0, stream>>>(
        query, Wofa_swz, b_off, b_attn, 256, ofa_h, 20000, 384);
    // softmax + deformable sampling -> out_pre fp16
    sample_kernel<<<2500, 256, 0, stream>>>(refp, ofa_h, value_h, out_pre_h);
    // output projection: [20000 x 256] = out_pre @ W_out + b_out (fp32 out)
    gemm_mfma<false, false><<<dim3(313, 4), 256, 0, stream>>>(
        out_pre_h, Wout_swz, b_out, b_out, 256, out, 20000, 256);
}

// Round 4
// 98.057 us; speedup vs baseline: 3.9675x; 1.3549x over previous
//
#include <hip/hip_runtime.h>

// MSDeformAttn — round 3: task-precompute + pk_fma sampling; hoisted fp16 cvt.
#define NB 2
#define NQ 10000
#define DM 256
#define NHEADS 8
#define NLEV 4
#define NPTS 4
#define DHEAD 32
#define LEN_IN 5440   // 64*64 + 32*32 + 16*16 + 8*8

typedef _Float16 f16x8 __attribute__((ext_vector_type(8)));
typedef _Float16 f16x4 __attribute__((ext_vector_type(4)));
typedef float    f32x4 __attribute__((ext_vector_type(4)));
typedef unsigned short u16x4 __attribute__((ext_vector_type(4)));

union TaskU {
    struct { f16x4 w; u16x4 p; } s;
    uint4 u;
};

// ---------------- weight pre-swizzle helper (proven in R2) ----------------
__device__ __forceinline__ void swz_one(const float* __restrict__ W, int Nw,
                                        int srcCol, int kbase,
                                        _Float16* __restrict__ dst) {
    f16x8 v;
    #pragma unroll
    for (int j = 0; j < 8; ++j) v[j] = (_Float16)W[(size_t)(kbase + j) * Nw + srcCol];
    *(f16x8*)dst = v;
}

// prep: weight swizzles + fp32->fp16 conversion of query and inflat.
// blocks 0..111: weights; 112..2611: query (5,120,000 elems); 2612..3971: inflat.
__global__ __launch_bounds__(256) void prep(const float* __restrict__ Wv,
                                            const float* __restrict__ Wo,
                                            const float* __restrict__ Wa,
                                            const float* __restrict__ Wout,
                                            const float* __restrict__ query,
                                            const float* __restrict__ inflat,
                                            _Float16* __restrict__ Wv_swz,
                                            _Float16* __restrict__ Wofa_swz,
                                            _Float16* __restrict__ Wout_swz,
                                            _Float16* __restrict__ query_h,
                                            _Float16* __restrict__ inflat_h) {
    const int b = blockIdx.x;
    const int t = threadIdx.x;
    if (b < 112) {
        const int tid = b * 256 + t;
        if (tid < 8192) {
            const int lane = tid & 63, tt = tid >> 6, kt = tt & 7, nt = tt >> 3;
            swz_one(Wv, 256, nt * 16 + (lane & 15), kt * 32 + (lane >> 4) * 8,
                    Wv_swz + ((size_t)(nt * 8 + kt) * 64 + lane) * 8);
        } else if (tid < 16384) {
            const int local = tid - 8192;
            const int lane = local & 63, tt = local >> 6, kt = tt & 7, nt = tt >> 3;
            swz_one(Wo, 256, nt * 16 + (lane & 15), kt * 32 + (lane >> 4) * 8,
                    Wofa_swz + ((size_t)(nt * 8 + kt) * 64 + lane) * 8);
        } else if (tid < 20480) {
            const int local = tid - 16384;
            const int lane = local & 63, tt = local >> 6, kt = tt & 7, nt = tt >> 3;
            swz_one(Wa, 128, nt * 16 + (lane & 15), kt * 32 + (lane >> 4) * 8,
                    Wofa_swz + ((size_t)((16 + nt) * 8 + kt) * 64 + lane) * 8);
        } else if (tid < 28672) {
            const int local = tid - 20480;
            const int lane = local & 63, tt = local >> 6, kt = tt & 7, nt = tt >> 3;
            swz_one(Wout, 256, nt * 16 + (lane & 15), kt * 32 + (lane >> 4) * 8,
                    Wout_swz + ((size_t)(nt * 8 + kt) * 64 + lane) * 8);
        }
    } else if (b < 112 + 2500) {
        const size_t e = ((size_t)(b - 112) * 256 + t) * 8;
        const float4 lo = *(const float4*)(query + e);
        const float4 hi = *(const float4*)(query + e + 4);
        f16x8 o;
        o[0] = (_Float16)lo.x; o[1] = (_Float16)lo.y; o[2] = (_Float16)lo.z; o[3] = (_Float16)lo.w;
        o[4] = (_Float16)hi.x; o[5] = (_Float16)hi.y; o[6] = (_Float16)hi.z; o[7] = (_Float16)hi.w;
        *(f16x8*)(query_h + e) = o;
    } else {
        const size_t e = ((size_t)(b - 2612) * 256 + t) * 8;
        const float4 lo = *(const float4*)(inflat + e);
        const float4 hi = *(const float4*)(inflat + e + 4);
        f16x8 o;
        o[0] = (_Float16)lo.x; o[1] = (_Float16)lo.y; o[2] = (_Float16)lo.z; o[3] = (_Float16)lo.w;
        o[4] = (_Float16)hi.x; o[5] = (_Float16)hi.y; o[6] = (_Float16)hi.z; o[7] = (_Float16)hi.w;
        *(f16x8*)(inflat_h + e) = o;
    }
}

// ---------------- MFMA GEMM: C[M][N] = A_h[M][256] @ Wswz + bias -----------
// 64x64 block tile, 4 waves (2x2), each wave 32x32 (2x2 16x16x32 fragments).
template<bool OUT_F16>
__global__ __launch_bounds__(256) void gemm_mfma(const _Float16* __restrict__ A,
                                                 const _Float16* __restrict__ Wswz,
                                                 const float* __restrict__ bias0,
                                                 const float* __restrict__ bias1,
                                                 int bsplit,
                                                 void* __restrict__ C_,
                                                 int M, int N) {
    const int lane = threadIdx.x & 63;
    const int w = threadIdx.x >> 6;
    const int wm = w & 1, wn = w >> 1;
    const int m0 = blockIdx.x * 64 + wm * 32;
    const int n0 = blockIdx.y * 64 + wn * 32;
    const int r = lane & 15;
    const int klane = (lane >> 4) * 8;

    const int rc0 = min(m0 + r, M - 1);
    const int rc1 = min(m0 + 16 + r, M - 1);
    const int ntile0 = n0 >> 4;

    f32x4 acc[2][2] = {};

    #pragma unroll
    for (int kt = 0; kt < 8; ++kt) {
        const f16x8 a0 = *(const f16x8*)(A + (size_t)rc0 * 256 + kt * 32 + klane);
        const f16x8 a1 = *(const f16x8*)(A + (size_t)rc1 * 256 + kt * 32 + klane);
        const f16x8 b0 = *(const f16x8*)(Wswz + ((size_t)((ntile0 + 0) * 8 + kt) * 64 + lane) * 8);
        const f16x8 b1 = *(const f16x8*)(Wswz + ((size_t)((ntile0 + 1) * 8 + kt) * 64 + lane) * 8);
        acc[0][0] = __builtin_amdgcn_mfma_f32_16x16x32_f16(a0, b0, acc[0][0], 0, 0, 0);
        acc[0][1] = __builtin_amdgcn_mfma_f32_16x16x32_f16(a0, b1, acc[0][1], 0, 0, 0);
        acc[1][0] = __builtin_amdgcn_mfma_f32_16x16x32_f16(a1, b0, acc[1][0], 0, 0, 0);
        acc[1][1] = __builtin_amdgcn_mfma_f32_16x16x32_f16(a1, b1, acc[1][1], 0, 0, 0);
    }

    #pragma unroll
    for (int j = 0; j < 2; ++j) {
        const int col = n0 + j * 16 + r;
        const float bb = (col < bsplit) ? bias0[col] : bias1[col - bsplit];
        #pragma unroll
        for (int i = 0; i < 2; ++i) {
            #pragma unroll
            for (int rr = 0; rr < 4; ++rr) {
                const int row = m0 + i * 16 + (lane >> 4) * 4 + rr;
                if (row < M) {
                    const float v = acc[i][j][rr] + bb;
                    if constexpr (OUT_F16)
                        ((_Float16*)C_)[(size_t)row * N + col] = (_Float16)v;
                    else
                        ((float*)C_)[(size_t)row * N + col] = v;
                }
            }
        }
    }
}

// ---------------- sampling: softmax + task precompute + pk_fma gather ------
__device__ __forceinline__ f16x8 sp8(_Float16 w) {
    return (f16x8){w, w, w, w, w, w, w, w};
}

__global__ __launch_bounds__(256) void sample_kernel(const float* __restrict__ refp,
                                                     const _Float16* __restrict__ ofa,
                                                     const _Float16* __restrict__ value,
                                                     _Float16* __restrict__ out_pre) {
    __shared__ float attns_s[8][128];     // post-softmax attn, f32
    __shared__ float refs[8][NLEV][2];
    __shared__ uint4 tasks[1024];         // [qh][16 swizzled slots] 16 B each

    const int t = threadIdx.x;
    const int blk = blockIdx.x;
    const int n = blk / (NQ / 8);
    const int q0 = (blk % (NQ / 8)) * 8;
    const size_t qb = (size_t)n * NQ + q0;

    // ---- refs + softmax (threads 0..63) ----
    if (t < 64) {
        {
            const int i = t >> 3, rem = t & 7;
            refs[i][rem >> 1][rem & 1] = refp[(qb + i) * NLEV * 2 + rem];
        }
        const int q = t >> 3, h = t & 7;
        const _Float16* arow = ofa + (qb + q) * 384 + 256 + h * 16;
        const f16x8 a0 = *(const f16x8*)arow;
        const f16x8 a1 = *(const f16x8*)(arow + 8);
        float a[16];
        #pragma unroll
        for (int j = 0; j < 8; ++j) { a[j] = (float)a0[j]; a[8 + j] = (float)a1[j]; }
        float m = a[0];
        #pragma unroll
        for (int j = 1; j < 16; ++j) m = fmaxf(m, a[j]);
        float s = 0.f;
        #pragma unroll
        for (int j = 0; j < 16; ++j) { const float e = __expf(a[j] - m); a[j] = e; s += e; }
        const float inv = 1.0f / s;
        #pragma unroll
        for (int j = 0; j < 16; ++j) attns_s[q][h * 16 + j] = a[j] * inv;
    }
    __syncthreads();

    // ---- phase A: 1024 (q,h,pt) tasks; thread t handles 4 pts of (q,h,lvl) ----
    {
        const int q = t >> 5, h = (t >> 2) & 7, lvl = t & 3, qh = t >> 2;
        constexpr int HS[4] = {64, 32, 16, 8};
        constexpr int ST[4] = {0, 4096, 5120, 5376};
        const int H_ = HS[lvl], W_ = HS[lvl], st = ST[lvl];
        const float fW = (float)W_, fH = (float)H_;
        const float invW = 1.0f / fW, invH = 1.0f / fH;
        const float rx = refs[q][lvl][0];
        const float ry = refs[q][lvl][1];
        const f16x8 off8 = *(const f16x8*)(ofa + (qb + q) * 384 + (h * 16 + lvl * 4) * 2);
        const f32x4 at4 = *(const f32x4*)&attns_s[q][h * 16 + lvl * 4];
        #pragma unroll
        for (int pt = 0; pt < NPTS; ++pt) {
            const float lx = rx + (float)off8[pt * 2]     * invW;
            const float ly = ry + (float)off8[pt * 2 + 1] * invH;
            const float aw = at4[pt];
            const float x = lx * fW - 0.5f;
            const float y = ly * fH - 0.5f;
            const float x0f = floorf(x);
            const float y0f = floorf(y);
            const float wx = x - x0f;
            const float wy = y - y0f;
            const int x0 = (int)x0f, y0 = (int)y0f;
            const int x1 = x0 + 1, y1 = y0 + 1;
            const int xc0 = min(max(x0, 0), W_ - 1);
            const int xc1 = min(max(x1, 0), W_ - 1);
            const int yc0 = min(max(y0, 0), H_ - 1);
            const int yc1 = min(max(y1, 0), H_ - 1);
            const bool vx0 = (x0 >= 0) & (x0 < W_);
            const bool vx1 = (x1 >= 0) & (x1 < W_);
            const bool vy0 = (y0 >= 0) & (y0 < H_);
            const bool vy1 = (y1 >= 0) & (y1 < H_);
            const float w00 = (vx0 & vy0) ? aw * (1.f - wx) * (1.f - wy) : 0.f;
            const float w01 = (vx1 & vy0) ? aw * wx         * (1.f - wy) : 0.f;
            const float w10 = (vx0 & vy1) ? aw * (1.f - wx) * wy         : 0.f;
            const float w11 = (vx1 & vy1) ? aw * wx         * wy         : 0.f;
            TaskU tu;
            tu.s.w = (f16x4){(_Float16)w00, (_Float16)w01, (_Float16)w10, (_Float16)w11};
            tu.s.p = (u16x4){(unsigned short)(st + yc0 * W_ + xc0),
                             (unsigned short)(st + yc0 * W_ + xc1),
                             (unsigned short)(st + yc1 * W_ + xc0),
                             (unsigned short)(st + yc1 * W_ + xc1)};
            tasks[qh * 16 + ((lvl * 4 + pt) ^ (qh & 15))] = tu.u;
        }
    }
    __syncthreads();

    // ---- phase B: thread = (q, h, g); gather f16x8, pk_fma accumulate ------
    {
        const int q = t >> 5, h = (t >> 2) & 7, g = t & 3, qh = t >> 2;
        const _Float16* vbase = value + (size_t)n * LEN_IN * DM + h * 32 + g * 8;
        f16x8 acc = {};
        #pragma unroll 4
        for (int ptIdx = 0; ptIdx < 16; ++ptIdx) {
            TaskU tu;
            tu.u = tasks[qh * 16 + (ptIdx ^ (qh & 15))];
            const f16x8 v0 = *(const f16x8*)(vbase + ((size_t)tu.s.p[0] << 8));
            const f16x8 v1 = *(const f16x8*)(vbase + ((size_t)tu.s.p[1] << 8));
            const f16x8 v2 = *(const f16x8*)(vbase + ((size_t)tu.s.p[2] << 8));
            const f16x8 v3 = *(const f16x8*)(vbase + ((size_t)tu.s.p[3] << 8));
            acc += v0 * sp8(tu.s.w[0]);
            acc += v1 * sp8(tu.s.w[1]);
            acc += v2 * sp8(tu.s.w[2]);
            acc += v3 * sp8(tu.s.w[3]);
        }
        *(f16x8*)(out_pre + (qb + q) * DM + h * 32 + g * 8) = acc;
    }
}

extern "C" void kernel_launch(void* const* d_in, const int* in_sizes, int n_in,
                              void* d_out, int out_size, void* d_ws, size_t ws_size,
                              hipStream_t stream) {
    const float* query  = (const float*)d_in[0];
    const float* refp   = (const float*)d_in[1];
    const float* inflat = (const float*)d_in[2];
    const float* W_value = (const float*)d_in[5];
    const float* b_value = (const float*)d_in[6];
    const float* W_off   = (const float*)d_in[7];
    const float* b_off   = (const float*)d_in[8];
    const float* W_attn  = (const float*)d_in[9];
    const float* b_attn  = (const float*)d_in[10];
    const float* W_out   = (const float*)d_in[11];
    const float* b_out   = (const float*)d_in[12];
    float* out = (float*)d_out;

    // ws layout (bytes) — identical footprint to R2 (31,301,632 proven):
    //   value_h   @ 0          : 5,570,560
    //   ofa_h     @ 5,570,560  : 15,360,000  (ends 20,930,560)
    //   out_pre_h @ 20,930,560 : 10,240,000  (ends 31,170,560)
    //   Wv_swz    @ 20,930,560 : 131,072  (alias out_pre — dead before sample)
    //   Wofa_swz  @ 21,061,632 : 196,608  (alias out_pre — dead before sample)
    //   Wout_swz  @ 31,170,560 : 131,072
    // d_out used as scratch before final GEMM writes it:
    //   query_h   @ d_out + 0          : 10,240,000
    //   inflat_h  @ d_out + 10,240,000 :  5,570,560   (d_out = 20,480,000 B)
    char* ws = (char*)d_ws;
    _Float16* value_h   = (_Float16*)(ws);
    _Float16* ofa_h     = (_Float16*)(ws + 5570560);
    _Float16* out_pre_h = (_Float16*)(ws + 20930560);
    _Float16* Wv_swz    = (_Float16*)(ws + 20930560);
    _Float16* Wofa_swz  = (_Float16*)(ws + 21061632);
    _Float16* Wout_swz  = (_Float16*)(ws + 31170560);
    _Float16* query_h   = (_Float16*)((char*)d_out);
    _Float16* inflat_h  = (_Float16*)((char*)d_out + 10240000);

    prep<<<3972, 256, 0, stream>>>(W_value, W_off, W_attn, W_out, query, inflat,
                                   Wv_swz, Wofa_swz, Wout_swz, query_h, inflat_h);
    // value projection: [10880 x 256]
    gemm_mfma<true><<<dim3(170, 4), 256, 0, stream>>>(
        inflat_h, Wv_swz, b_value, b_value, 256, value_h, 10880, 256);
    // off+attn projection: [20000 x 384]
    gemm_mfma<true><<<dim3(313, 6), 256, 0, stream>>>(
        query_h, Wofa_swz, b_off, b_attn, 256, ofa_h, 20000, 384);
    // softmax + task precompute + gather
    sample_kernel<<<2500, 256, 0, stream>>>(refp, ofa_h, value_h, out_pre_h);
    // output projection: [20000 x 256] fp32 out (overwrites d_out scratch)
    gemm_mfma<false><<<dim3(313, 4), 256, 0, stream>>>(
        out_pre_h, Wout_swz, b_out, b_out, 256, out, 20000, 256);
}